// Round 3
// baseline (431.114 us; speedup 1.0000x reference)
//
#include <hip/hip_runtime.h>
#include <hip/hip_bf16.h>

// VQ-VAE vector quantizer, MI355X.
// z: (16,512,64,64) f32   codebook: (1024,512) f32
// d_out is FLOAT32 (reference outputs are f32; graded vs bf16-rounded ref,
// threshold 20.48): z_q (33554432), loss (1), idx (65536) concatenated.

typedef _Float16 h8 __attribute__((ext_vector_type(8)));
typedef _Float16 h4 __attribute__((ext_vector_type(4)));
typedef float f32x16 __attribute__((ext_vector_type(16)));

#define N_PIX     65536
#define OUT_LOSS  33554432
#define OUT_IDX   33554433
#define MARGIN_T  0.15f     // ~9 sigma of fp16-dot noise on the t-gap

__device__ __forceinline__ void gload_lds16(const void* g, void* l) {
  __builtin_amdgcn_global_load_lds(
      (const __attribute__((address_space(1))) void*)g,
      (__attribute__((address_space(3))) void*)l, 16, 0, 0);
}

// ---- K0: codebook fp32 -> fp16, ||c||^2, and workspace init -------------------
__global__ __launch_bounds__(64) void k0_prep(
    const float* __restrict__ cb, unsigned short* __restrict__ cb16,
    float* __restrict__ cnorm, int* __restrict__ flagcount, float* __restrict__ loss_acc,
    int* __restrict__ idx_ws, unsigned long long* __restrict__ packed_ws)
{
  const int r = blockIdx.x, l = threadIdx.x;
  const float* row = cb + (size_t)r * 512;
  float4 a  = *(const float4*)(row + l * 8);
  float4 b4 = *(const float4*)(row + l * 8 + 4);
  h8 hv;
  hv[0] = (_Float16)a.x;  hv[1] = (_Float16)a.y;  hv[2] = (_Float16)a.z;  hv[3] = (_Float16)a.w;
  hv[4] = (_Float16)b4.x; hv[5] = (_Float16)b4.y; hv[6] = (_Float16)b4.z; hv[7] = (_Float16)b4.w;
  *reinterpret_cast<h8*>(cb16 + (size_t)r * 512 + l * 8) = hv;
  float s = a.x*a.x + a.y*a.y + a.z*a.z + a.w*a.w
          + b4.x*b4.x + b4.y*b4.y + b4.z*b4.z + b4.w*b4.w;
  #pragma unroll
  for (int off = 1; off < 64; off <<= 1) s += __shfl_xor(s, off);
  if (l == 0) cnorm[r] = s;
  const int pix = (r << 6) + l;        // 1024 x 64 == 65536 pixels
  idx_ws[pix] = (int)0x80000000;       // "flagged" sentinel
  packed_ws[pix] = ~0ull;              // worst key; K2 atomicMin improves it
  if (r == 0 && l == 0) { *flagcount = 0; *loss_acc = 0.f; }
}

// ---- K1: fp16 MFMA distance scan + top2/argmin + flagging ---------------------
// 256 thr (4 waves), 128 pixels/block. Dynamic LDS = 131072.
// [0,128K) z-tile fp16 (phase 1-2); then [0,32K) buf0, [32K,64K) buf1, [64K,68K) cnorm.
__global__ __launch_bounds__(256, 1) void k1_main(
    const float* __restrict__ z, const unsigned short* __restrict__ cb16,
    const float* __restrict__ cnorm,
    int* __restrict__ idx_ws, int* __restrict__ flaglist, int* __restrict__ flagcount)
{
  extern __shared__ char smem[];
  float* cnorm_lds = reinterpret_cast<float*>(smem + 65536);
  const int tid  = threadIdx.x;
  const int lane = tid & 63;
  const int wave = tid >> 6;           // 0..3
  const int px0  = blockIdx.x << 7;    // 128 px/block
  const int b    = px0 >> 12;
  const int hw0  = px0 & 4095;
  const float* zbase = z + ((size_t)b * 512) * 4096 + hw0;

  // phase 1: z (channel-major) -> LDS fp16 [pixel][k], row 1024B, byte ^= (row&15)<<4
  for (int it = 0; it < 16; ++it) {
    int w  = it * 256 + tid;
    int cg = w >> 5;               // channel quad 0..127
    int p  = (w & 31) * 4;         // pixel quad base
    const float* src = zbase + (size_t)cg * 4 * 4096 + p;
    float4 v0 = *(const float4*)(src);
    float4 v1 = *(const float4*)(src + 4096);
    float4 v2 = *(const float4*)(src + 8192);
    float4 v3 = *(const float4*)(src + 12288);
    const float* f0 = reinterpret_cast<const float*>(&v0);
    const float* f1 = reinterpret_cast<const float*>(&v1);
    const float* f2 = reinterpret_cast<const float*>(&v2);
    const float* f3 = reinterpret_cast<const float*>(&v3);
    #pragma unroll
    for (int dp = 0; dp < 4; ++dp) {
      h4 hv;
      hv[0] = (_Float16)f0[dp]; hv[1] = (_Float16)f1[dp];
      hv[2] = (_Float16)f2[dp]; hv[3] = (_Float16)f3[dp];
      int row = p + dp;
      int off = (row << 10) + (cg << 3);
      off ^= (row & 15) << 4;
      *reinterpret_cast<h4*>(smem + off) = hv;
    }
  }
  __syncthreads();

  // phase 2: per-wave B-fragments (32 pixels x K=512) into VGPRs
  const int pxl   = lane & 31;
  const int khalf = lane >> 5;
  h8 bfrag[32];
  {
    int row = wave * 32 + pxl;
    int sw  = (row & 15) << 4;
    #pragma unroll
    for (int s = 0; s < 32; ++s) {
      int off = ((row << 10) + (s << 5) + (khalf << 4)) ^ sw;
      bfrag[s] = *reinterpret_cast<const h8*>(smem + off);
    }
  }
  __syncthreads();

  for (int i = tid; i < 1024; i += 256) cnorm_lds[i] = cnorm[i];
  {
    const char* src = reinterpret_cast<const char*>(cb16);
    #pragma unroll
    for (int i = 0; i < 8; ++i) {
      int o  = (i << 12) + (wave << 10) + (lane << 4);
      int so = o ^ (((o >> 10) & 15) << 4);
      gload_lds16(src + so, smem + (i << 12) + (wave << 10));
    }
  }
  asm volatile("s_waitcnt vmcnt(0)" ::: "memory");
  __syncthreads();

  float v0r = INFINITY, v1r = INFINITY;
  int   i0r = 0;

  for (int ch = 0; ch < 32; ++ch) {    // 32 chunks x 32 codebook rows
    char* cbuf = smem + ((ch & 1) << 15);
    if (ch < 31) {
      const char* src = reinterpret_cast<const char*>(cb16) + ((ch + 1) << 15);
      char* dbuf = smem + (((ch & 1) ^ 1) << 15);
      #pragma unroll
      for (int i = 0; i < 8; ++i) {
        int o  = (i << 12) + (wave << 10) + (lane << 4);
        int so = o ^ (((o >> 10) & 15) << 4);
        gload_lds16(src + so, dbuf + (i << 12) + (wave << 10));
      }
    }
    f32x16 acca, accb;
    #pragma unroll
    for (int i = 0; i < 16; ++i) { acca[i] = 0.f; accb[i] = 0.f; }
    {
      const int sw = (pxl & 15) << 4;
      #pragma unroll
      for (int s = 0; s < 16; ++s) {
        int oa = ((pxl << 10) + (s << 5) + (khalf << 4)) ^ sw;
        h8 a0 = *reinterpret_cast<const h8*>(cbuf + oa);
        h8 a1 = *reinterpret_cast<const h8*>(cbuf + oa + 512);
        acca = __builtin_amdgcn_mfma_f32_32x32x16_f16(a0, bfrag[s],      acca, 0, 0, 0);
        accb = __builtin_amdgcn_mfma_f32_32x32x16_f16(a1, bfrag[s + 16], accb, 0, 0, 0);
      }
    }
    const int jbase = (ch << 5) + (khalf << 2);
    #pragma unroll
    for (int r = 0; r < 16; ++r) {
      int j = jbase + ((r & 3) + ((r >> 2) << 3));
      float sc = fmaf(0.5f, cnorm_lds[j], -(acca[r] + accb[r]));
      bool better = (sc < v0r) || (sc == v0r && j < i0r);
      v1r = better ? v0r : fminf(v1r, sc);
      if (better) { v0r = sc; i0r = j; }
    }
    asm volatile("s_waitcnt vmcnt(0)" ::: "memory");
    __syncthreads();
  }

  {
    float ov0 = __shfl_xor(v0r, 32);
    float ov1 = __shfl_xor(v1r, 32);
    int   oi0 = __shfl_xor(i0r, 32);
    bool take = (ov0 < v0r) || (ov0 == v0r && oi0 < i0r);
    float loser = take ? v0r : ov0;
    v1r = fminf(fminf(v1r, ov1), loser);
    if (take) { v0r = ov0; i0r = oi0; }
  }

  if (lane < 32) {
    const int pix = px0 + wave * 32 + lane;
    bool ok   = (v1r - v0r >= MARGIN_T) && ((unsigned)i0r < 1024u);
    bool flag = !ok;
    idx_ws[pix] = flag ? (int)0x80000000 : i0r;
    unsigned long long mask = __ballot(flag);
    if (mask) {
      int leader = __ffsll((unsigned long long)mask) - 1;
      int basev = 0;
      if (lane == leader) basev = atomicAdd(flagcount, __popcll(mask));
      basev = __shfl(basev, leader);
      if (flag) {
        int pos = __popcll(mask & ((1ull << lane) - 1ull));
        flaglist[basev + pos] = pix;
      }
    }
  }
}

// ---- K2: exact fp64 re-rank of flagged pixels ---------------------------------
__global__ __launch_bounds__(256) void k2_rescan(
    const float* __restrict__ z, const float* __restrict__ cb,
    const int* __restrict__ flaglist, const int* __restrict__ flagcount,
    unsigned long long* __restrict__ packed_ws)
{
  __shared__ float zb[16][512];
  __shared__ unsigned long long best[16];
  __shared__ int pixl[16];
  const int t = threadIdx.x;
  const int nflag = *flagcount;
  const int ntasks = ((nflag + 15) >> 4) << 2;
  for (int task = blockIdx.x; task < ntasks; task += gridDim.x) {
    const int g = task >> 2, q = task & 3;
    int rem = nflag - (g << 4);
    const int npx = rem < 16 ? rem : 16;
    if (t < 16) {
      best[t] = ~0ull;
      pixl[t] = (t < npx) ? flaglist[(g << 4) + t] : 0;
    }
    __syncthreads();
    for (int i = t; i < (npx << 9); i += 256) {
      int p = i >> 9, c = i & 511;
      int pix = pixl[p];
      zb[p][c] = z[((size_t)(pix >> 12) * 512 + c) * 4096 + (pix & 4095)];
    }
    __syncthreads();
    const int j = (q << 8) + t;
    const float* row = cb + (size_t)j * 512;
    double dot[16];
    #pragma unroll
    for (int p = 0; p < 16; ++p) dot[p] = 0.0;
    double cn = 0.0;
    for (int k = 0; k < 512; k += 4) {
      float4 cv = *(const float4*)(row + k);
      double c0 = cv.x, c1 = cv.y, c2 = cv.z, c3 = cv.w;
      cn = fma(c0, c0, cn); cn = fma(c1, c1, cn);
      cn = fma(c2, c2, cn); cn = fma(c3, c3, cn);
      #pragma unroll
      for (int p = 0; p < 16; ++p) {
        dot[p] = fma(c0, (double)zb[p][k + 0], dot[p]);
        dot[p] = fma(c1, (double)zb[p][k + 1], dot[p]);
        dot[p] = fma(c2, (double)zb[p][k + 2], dot[p]);
        dot[p] = fma(c3, (double)zb[p][k + 3], dot[p]);
      }
    }
    #pragma unroll
    for (int p = 0; p < 16; ++p) {
      if (p < npx) {
        double d = fma(-2.0, dot[p], cn);   // ||z||^2 per-pixel constant: dropped
        unsigned long long u = (unsigned long long)__double_as_longlong(d);
        u = (u >> 63) ? ~u : (u | 0x8000000000000000ull);     // sortable
        unsigned long long pk = (u & ~1023ull) | (unsigned long long)j;
        atomicMin(&best[p], pk);
      }
    }
    __syncthreads();
    if (t < npx) atomicMin(&packed_ws[pixl[t]], best[t]);
    __syncthreads();
  }
}

// ---- K3: gather + transpose-write z_q (f32), idx (f32), loss ------------------
__global__ __launch_bounds__(256) void k3_out(
    const float* __restrict__ z, const float* __restrict__ cb,
    const int* __restrict__ idx_ws, const unsigned long long* __restrict__ packed_ws,
    float* __restrict__ out, float* __restrict__ loss_acc)
{
  __shared__ float rows[16 * 513];
  __shared__ int idxs[16];
  const int t = threadIdx.x;
  const int pix0 = blockIdx.x << 4;      // 16 px / block
  const int b = pix0 >> 12, hw0 = pix0 & 4095;
  if (t < 16) {
    int pix = pix0 + t;
    int v = idx_ws[pix];
    unsigned j = (v < 0) ? (unsigned)(packed_ws[pix] & 1023ull) : (unsigned)v;
    j &= 1023u;
    idxs[t] = (int)j;
    out[OUT_IDX + pix] = (float)j;
  }
  __syncthreads();
  for (int i = t; i < 16 * 128; i += 256) {
    int r = i >> 7, kq = (i & 127) << 2;
    float4 v = *(const float4*)(cb + (size_t)idxs[r] * 512 + kq);
    float* dst = rows + r * 513 + kq;
    dst[0] = v.x; dst[1] = v.y; dst[2] = v.z; dst[3] = v.w;
  }
  __syncthreads();
  const int pl = (t & 3) << 2;  // pixel quad base {0,4,8,12}
  const int cg = t >> 2;        // 0..63
  float acc = 0.f;
  for (int c0 = 0; c0 < 512; c0 += 64) {
    int c = c0 + cg;
    size_t go = ((size_t)(b * 512 + c)) * 4096 + hw0 + pl;
    float4 zv = *(const float4*)(z + go);
    float q0 = rows[(pl + 0) * 513 + c], q1 = rows[(pl + 1) * 513 + c];
    float q2 = rows[(pl + 2) * 513 + c], q3 = rows[(pl + 3) * 513 + c];
    float d0 = q0 - zv.x, d1 = q1 - zv.y, d2 = q2 - zv.z, d3 = q3 - zv.w;
    acc = fmaf(d0, d0, acc); acc = fmaf(d1, d1, acc);
    acc = fmaf(d2, d2, acc); acc = fmaf(d3, d3, acc);
    float4 qv;
    qv.x = zv.x + d0; qv.y = zv.y + d1;   // mimic ref STE rounding: zp + (z_q - zp)
    qv.z = zv.z + d2; qv.w = zv.w + d3;
    *reinterpret_cast<float4*>(out + go) = qv;
  }
  #pragma unroll
  for (int off = 32; off > 0; off >>= 1) acc += __shfl_down(acc, off);
  __shared__ float wsum[4];
  if ((t & 63) == 0) wsum[t >> 6] = acc;
  __syncthreads();
  if (t == 0) atomicAdd(loss_acc, wsum[0] + wsum[1] + wsum[2] + wsum[3]);
}

__global__ void k4_loss(const float* __restrict__ loss_acc, float* __restrict__ out)
{
  if (threadIdx.x == 0 && blockIdx.x == 0)
    out[OUT_LOSS] = loss_acc[0] * (1.25f / 33554432.f);
}

// ---- launch --------------------------------------------------------------------
extern "C" void kernel_launch(void* const* d_in, const int* in_sizes, int n_in,
                              void* d_out, int out_size, void* d_ws, size_t ws_size,
                              hipStream_t stream) {
  const float* z  = (const float*)d_in[0];
  const float* cb = (const float*)d_in[1];
  float* out = (float*)d_out;
  char* ws = (char*)d_ws;
  unsigned short*      cb16      = (unsigned short*)(ws);                 // 1 MB
  float*               cnorm     = (float*)(ws + 1048576);                // 4 KB
  int*                 idx_ws    = (int*)(ws + 1052672);                  // 256 KB
  unsigned long long*  packed_ws = (unsigned long long*)(ws + 1314816);   // 512 KB
  int*                 flaglist  = (int*)(ws + 1839104);                  // 256 KB
  int*                 flagcount = (int*)(ws + 2101248);
  float*               loss_acc  = (float*)(ws + 2101252);

  (void)hipFuncSetAttribute((const void*)k1_main,
        hipFuncAttributeMaxDynamicSharedMemorySize, 131072);

  k0_prep<<<1024, 64, 0, stream>>>(cb, cb16, cnorm, flagcount, loss_acc, idx_ws, packed_ws);
  k1_main<<<512, 256, 131072, stream>>>(z, cb16, cnorm, idx_ws, flaglist, flagcount);
  k2_rescan<<<512, 256, 0, stream>>>(z, cb, flaglist, flagcount, packed_ws);
  k3_out<<<4096, 256, 0, stream>>>(z, cb, idx_ws, packed_ws, out, loss_acc);
  k4_loss<<<1, 1, 0, stream>>>(loss_acc, out);
}